// Round 6
// baseline (682.317 us; speedup 1.0000x reference)
//
#include <hip/hip_runtime.h>

// Problem dims (fixed)
#define BB 2
#define LL 1024
#define DD 1024
#define HH 16
#define HD 64
#define DFFN 4096
#define MM (BB*LL)   // 2048 rows
#define QS 3072      // fused QKV row stride

using u16 = unsigned short;
typedef __bf16 bf16x8 __attribute__((ext_vector_type(8)));
typedef float f32x4 __attribute__((ext_vector_type(4)));

__device__ __forceinline__ float b2f(u16 u) {
  union { unsigned int i; float f; } v; v.i = ((unsigned int)u) << 16; return v.f;
}
__device__ __forceinline__ u16 f2b(float f) {
  union { float f; unsigned int i; } v; v.f = f;
  unsigned int x = v.i;
  return (u16)((x + 0x7fffu + ((x >> 16) & 1u)) >> 16);  // RNE, finite values
}
__device__ __forceinline__ float gelu_exact(float x) {
  return 0.5f * x * (1.0f + erff(x * 0.70710678118654752f));
}
__device__ __forceinline__ void gl2lds16(const void* g, void* l) {
  __builtin_amdgcn_global_load_lds((const __attribute__((address_space(1))) void*)g,
                                   (__attribute__((address_space(3))) void*)l, 16, 0, 0);
}
__device__ __forceinline__ uint4 pack8(const float4& a, const float4& b) {
  uint4 o;
  o.x = (unsigned)f2b(a.x) | ((unsigned)f2b(a.y) << 16);
  o.y = (unsigned)f2b(a.z) | ((unsigned)f2b(a.w) << 16);
  o.z = (unsigned)f2b(b.x) | ((unsigned)f2b(b.y) << 16);
  o.w = (unsigned)f2b(b.z) | ((unsigned)f2b(b.w) << 16);
  return o;
}

// ---- GEMM building blocks (all indices compile-time; LDS buffers passed statically) ----
template<int IB, int NT>
__device__ __forceinline__ void loadW(const float* __restrict__ W, int n0, int K, int kt,
                                      int t, float4 w[IB][2]) {
  #pragma unroll
  for (int i = 0; i < IB; i++) {
    const int c = i * NT + t;
    const float* wp = W + (size_t)(n0 + (c >> 2)) * K + kt + (c & 3) * 8;
    w[i][0] = reinterpret_cast<const float4*>(wp)[0];
    w[i][1] = reinterpret_cast<const float4*>(wp)[1];
  }
}
template<int IB, int NT>
__device__ __forceinline__ void cvtW(u16* Bsb, int t, const float4 w[IB][2]) {
  #pragma unroll
  for (int i = 0; i < IB; i++) {
    const int c = i * NT + t;
    *reinterpret_cast<uint4*>(&Bsb[c * 8]) = pack8(w[i][0], w[i][1]);
  }
}
template<int IA, int NT>
__device__ __forceinline__ void dmaA(const u16* __restrict__ A, int m0, int K, int kt,
                                     int t, u16* Asb) {
  #pragma unroll
  for (int i = 0; i < IA; i++) {
    const int c = i * NT + t;
    gl2lds16(A + (size_t)(m0 + (c >> 2)) * K + kt + (c & 3) * 8, &Asb[c * 8]);
  }
}
__device__ __forceinline__ void mfma_tile(const u16* Asb, const u16* Bsb,
                                          int wm, int wn, int fr, int fq, f32x4 acc[4][4]) {
  bf16x8 af[4], bfv[4];
  #pragma unroll
  for (int i = 0; i < 4; i++)
    af[i] = *reinterpret_cast<const bf16x8*>(&Asb[(wm + i * 16 + fr) * 32 + fq * 8]);
  #pragma unroll
  for (int j = 0; j < 4; j++)
    bfv[j] = *reinterpret_cast<const bf16x8*>(&Bsb[(wn + j * 16 + fr) * 32 + fq * 8]);
  #pragma unroll
  for (int i = 0; i < 4; i++)
    #pragma unroll
    for (int j = 0; j < 4; j++)
      acc[i][j] = __builtin_amdgcn_mfma_f32_16x16x32_bf16(af[i], bfv[j], acc[i][j], 0, 0, 0);
}

// ---------------- MFMA GEMM: C[M,N](bf16) = A(bf16) @ W(fp32,[N,K])^T, fused cast ----------------
// Double-buffered LDS; DMA-A prefetch distance 1, W-register prefetch distance 2.
// QKV3: W selected from {W0,W1,W2} by output-column block (each 1024 wide).
template<int BM, int BN, int ACT, int QKV3>
__global__ __launch_bounds__((BM/64)*(BN/64)*64)
void mfma_gemm(const u16* __restrict__ A, const float* __restrict__ W0,
               const float* __restrict__ W1, const float* __restrict__ W2,
               u16* __restrict__ Cb, int N, int K) {
  constexpr int WCOLS = BN / 64;
  constexpr int NW = (BM / 64) * WCOLS;
  constexpr int NT = NW * 64;
  constexpr int IA = BM * 4 / NT, IB = BN * 4 / NT;
  __shared__ u16 As[2][BM * 32];
  __shared__ u16 Bs[2][BN * 32];
  const int t = threadIdx.x;
  const int lane = t & 63, w = t >> 6;
  const int wm = (w / WCOLS) * 64, wn = (w % WCOLS) * 64;
  const int m0 = blockIdx.y * BM;
  const int n0out = blockIdx.x * BN;
  const float* W = W0;
  int n0 = n0out;
  if (QKV3) {
    const int sel = n0out >> 10;
    W = (sel == 0) ? W0 : (sel == 1) ? W1 : W2;
    n0 = n0out & 1023;
  }
  const int fr = lane & 15, fq = lane >> 4;

  f32x4 acc[4][4] = {};
  float4 wA[IB][2], wB[IB][2];

  // prologue: stage tile 0 into buf0; preload W tile 1 into wB
  loadW<IB, NT>(W, n0, K, 0, t, wA);
  dmaA<IA, NT>(A, m0, K, 0, t, &As[0][0]);
  loadW<IB, NT>(W, n0, K, 32, t, wB);
  cvtW<IB, NT>(&Bs[0][0], t, wA);

  for (int kt = 0; kt < K; kt += 64) {
    // sub-iter 0: consume buf0 (tile kt)
    __syncthreads();
    if (kt + 64 < K) loadW<IB, NT>(W, n0, K, kt + 64, t, wA);
    if (kt + 32 < K) dmaA<IA, NT>(A, m0, K, kt + 32, t, &As[1][0]);
    mfma_tile(&As[0][0], &Bs[0][0], wm, wn, fr, fq, acc);
    if (kt + 32 < K) cvtW<IB, NT>(&Bs[1][0], t, wB);
    if (kt + 32 >= K) break;
    // sub-iter 1: consume buf1 (tile kt+32)
    __syncthreads();
    if (kt + 96 < K) loadW<IB, NT>(W, n0, K, kt + 96, t, wB);
    if (kt + 64 < K) dmaA<IA, NT>(A, m0, K, kt + 64, t, &As[0][0]);
    mfma_tile(&As[1][0], &Bs[1][0], wm, wn, fr, fq, acc);
    if (kt + 64 < K) cvtW<IB, NT>(&Bs[0][0], t, wA);
  }

  #pragma unroll
  for (int i = 0; i < 4; i++)
    #pragma unroll
    for (int j = 0; j < 4; j++)
      #pragma unroll
      for (int r = 0; r < 4; r++) {
        const int row = m0 + wm + i * 16 + fq * 4 + r;
        const int col = n0out + wn + j * 16 + fr;
        float val = acc[i][j][r];
        if (ACT == 1) val = gelu_exact(val);
        Cb[(size_t)row * N + col] = f2b(val);
      }
}

// ---------------- split-K MFMA GEMM: Co(f32) += A @ W(fp32)^T  (Co pre-initialized) ----------------
template<int SPLIT>
__global__ __launch_bounds__(256)
void mfma_gemm_sk(const u16* __restrict__ A, const float* __restrict__ W,
                  float* __restrict__ Co, int N, int K) {
  constexpr int BM = 128, BN = 128, NT = 256, IA = 2, IB = 2;
  __shared__ u16 As[2][BM * 32];
  __shared__ u16 Bs[2][BN * 32];
  const int t = threadIdx.x;
  const int lane = t & 63, w = t >> 6;
  const int wm = (w >> 1) * 64, wn = (w & 1) * 64;
  const int m0 = blockIdx.y * BM, n0 = blockIdx.x * BN;
  const int fr = lane & 15, fq = lane >> 4;
  const int Kc = K / SPLIT, k0 = blockIdx.z * Kc, kend = k0 + Kc;

  f32x4 acc[4][4] = {};
  float4 wA[IB][2], wB[IB][2];

  loadW<IB, NT>(W, n0, K, k0, t, wA);
  dmaA<IA, NT>(A, m0, K, k0, t, &As[0][0]);
  loadW<IB, NT>(W, n0, K, k0 + 32, t, wB);
  cvtW<IB, NT>(&Bs[0][0], t, wA);

  for (int kt = k0; kt < kend; kt += 64) {
    __syncthreads();
    if (kt + 64 < kend) loadW<IB, NT>(W, n0, K, kt + 64, t, wA);
    if (kt + 32 < kend) dmaA<IA, NT>(A, m0, K, kt + 32, t, &As[1][0]);
    mfma_tile(&As[0][0], &Bs[0][0], wm, wn, fr, fq, acc);
    if (kt + 32 < kend) cvtW<IB, NT>(&Bs[1][0], t, wB);
    if (kt + 32 >= kend) break;
    __syncthreads();
    if (kt + 96 < kend) loadW<IB, NT>(W, n0, K, kt + 96, t, wB);
    if (kt + 64 < kend) dmaA<IA, NT>(A, m0, K, kt + 64, t, &As[0][0]);
    mfma_tile(&As[1][0], &Bs[1][0], wm, wn, fr, fq, acc);
    if (kt + 64 < kend) cvtW<IB, NT>(&Bs[0][0], t, wA);
  }

  #pragma unroll
  for (int i = 0; i < 4; i++)
    #pragma unroll
    for (int j = 0; j < 4; j++)
      #pragma unroll
      for (int r = 0; r < 4; r++) {
        const int row = m0 + wm + i * 16 + fq * 4 + r;
        const int col = n0 + wn + j * 16 + fr;
        unsafeAtomicAdd(&Co[(size_t)row * N + col], acc[i][j][r]);
      }
}

// ---------------- out = resid (+ bias), fp32 ----------------
__global__ __launch_bounds__(256) void init_out_kernel(float* __restrict__ out,
                                                       const float* __restrict__ resid,
                                                       const float* __restrict__ bias) {
  const int i = blockIdx.x * 256 + threadIdx.x;   // float4 index
  float4 v = reinterpret_cast<const float4*>(resid)[i];
  if (bias != nullptr) {
    const float4 bv = *reinterpret_cast<const float4*>(bias + ((i * 4) & (DD - 1)));
    v.x += bv.x; v.y += bv.y; v.z += bv.z; v.w += bv.w;
  }
  reinterpret_cast<float4*>(out)[i] = v;
}

// ---------------- rmsnorm (fp32 in, fp32 weight, bf16 out) ----------------
__global__ __launch_bounds__(256) void rmsnorm_kernel(const float* __restrict__ x,
                                                      const float* __restrict__ w,
                                                      u16* __restrict__ out) {
  const int row = blockIdx.x, t = threadIdx.x;
  const float4 v = reinterpret_cast<const float4*>(x + (size_t)row * DD)[t];
  float ss = v.x*v.x + v.y*v.y + v.z*v.z + v.w*v.w;
  #pragma unroll
  for (int o = 32; o > 0; o >>= 1) ss += __shfl_down(ss, o);
  __shared__ float red[4];
  if ((t & 63) == 0) red[t >> 6] = ss;
  __syncthreads();
  const float inv = rsqrtf((red[0] + red[1] + red[2] + red[3]) * (1.0f / DD) + 1e-5f);
  const float4 wv = reinterpret_cast<const float4*>(w)[t];
  ushort4 o;
  o.x = f2b(v.x * inv * wv.x);
  o.y = f2b(v.y * inv * wv.y);
  o.z = f2b(v.z * inv * wv.z);
  o.w = f2b(v.w * inv * wv.w);
  reinterpret_cast<ushort4*>(out + (size_t)row * DD)[t] = o;
}

// ---------------- K/V transpose via LDS, coalesced both sides ----------------
__global__ __launch_bounds__(256) void kv_trans(const u16* __restrict__ QKV,
                                                u16* __restrict__ Kt, u16* __restrict__ Vt) {
  __shared__ u16 T[64][72];
  const int tile = blockIdx.x;
  const int h2 = blockIdx.y;             // h = h2&15, which = h2>>4 (0=K, 1=V)
  const int b = blockIdx.z;
  const int h = h2 & 15, which = h2 >> 4;
  const int t = threadIdx.x;
  const int pos = t >> 2, d0 = (t & 3) * 16;
  const u16* src = QKV + ((size_t)(b * LL) + tile * 64 + pos) * QS + 1024 + which * 1024 + h * HD + d0;
  union { uint4 u[2]; u16 s[16]; } pk;
  pk.u[0] = reinterpret_cast<const uint4*>(src)[0];
  pk.u[1] = reinterpret_cast<const uint4*>(src)[1];
  #pragma unroll
  for (int j = 0; j < 16; j++) T[d0 + j][pos] = pk.s[j];
  __syncthreads();
  const int d = t >> 2, p0 = (t & 3) * 16;
  u16* dst = (which ? Vt : Kt) + ((size_t)(b * HH + h) * HD + d) * LL + tile * 64 + p0;
  union { uint4 u[2]; u16 s[16]; } ok;
  #pragma unroll
  for (int j = 0; j < 16; j++) ok.s[j] = T[d][p0 + j];
  reinterpret_cast<uint4*>(dst)[0] = ok.u[0];
  reinterpret_cast<uint4*>(dst)[1] = ok.u[1];
}

// ---------------- attention phase 1 ----------------
__global__ __launch_bounds__(256) void attn_phase1(const u16* __restrict__ QKV,
                                                   const u16* __restrict__ Kt,
                                                   const u16* __restrict__ Vt,
                                                   u16* __restrict__ Oa,
                                                   u16* __restrict__ Slt) {
  __shared__ u16 Ss[4][16][64];
  const int tile = blockIdx.x, h = blockIdx.y, b = blockIdx.z;
  const int t = threadIdx.x, lane = t & 63, w = t >> 6;
  const int fr = lane & 15, fq = lane >> 4;
  const size_t tok0 = (size_t)(b * LL + tile * 64);
  const size_t bh = (size_t)(b * HH + h);
  const u16* Qb  = QKV + tok0 * QS + h * HD;
  const u16* Kb  = Qb + 1024;
  const u16* Ktb = Kt + bh * (HD * LL) + tile * 64;
  const u16* Vtb = Vt + bh * (HD * LL) + tile * 64;

  // ---- S = Q K^T ----
  bf16x8 aq[2], bk[4][2];
  #pragma unroll
  for (int kh = 0; kh < 2; kh++)
    aq[kh] = *reinterpret_cast<const bf16x8*>(Qb + (size_t)(16*w + fr) * QS + kh*32 + fq*8);
  #pragma unroll
  for (int n4 = 0; n4 < 4; n4++)
    #pragma unroll
    for (int kh = 0; kh < 2; kh++)
      bk[n4][kh] = *reinterpret_cast<const bf16x8*>(Kb + (size_t)(16*n4 + fr) * QS + kh*32 + fq*8);
  f32x4 sacc[4] = {};
  #pragma unroll
  for (int n4 = 0; n4 < 4; n4++) {
    sacc[n4] = __builtin_amdgcn_mfma_f32_16x16x32_bf16(aq[0], bk[n4][0], sacc[n4], 0, 0, 0);
    sacc[n4] = __builtin_amdgcn_mfma_f32_16x16x32_bf16(aq[1], bk[n4][1], sacc[n4], 0, 0, 0);
  }
  #pragma unroll
  for (int n4 = 0; n4 < 4; n4++)
    #pragma unroll
    for (int r = 0; r < 4; r++) {
      const bool keep = (16*w + 4*fq + r) >= (16*n4 + fr);
      Ss[w][4*fq + r][16*n4 + fr] = keep ? f2b(sacc[n4][r]) : (u16)0;
    }
  __syncthreads();

  // ---- Slt = V^T K ----
  bf16x8 va[2], kt[4][2];
  #pragma unroll
  for (int kh = 0; kh < 2; kh++)
    va[kh] = *reinterpret_cast<const bf16x8*>(Vtb + (size_t)(16*w + fr) * LL + kh*32 + fq*8);
  #pragma unroll
  for (int n4 = 0; n4 < 4; n4++)
    #pragma unroll
    for (int kh = 0; kh < 2; kh++)
      kt[n4][kh] = *reinterpret_cast<const bf16x8*>(Ktb + (size_t)(16*n4 + fr) * LL + kh*32 + fq*8);
  f32x4 lacc[4] = {};
  #pragma unroll
  for (int n4 = 0; n4 < 4; n4++) {
    lacc[n4] = __builtin_amdgcn_mfma_f32_16x16x32_bf16(va[0], kt[n4][0], lacc[n4], 0, 0, 0);
    lacc[n4] = __builtin_amdgcn_mfma_f32_16x16x32_bf16(va[1], kt[n4][1], lacc[n4], 0, 0, 0);
  }
  u16* So = Slt + (bh * 16 + tile) * 4096;
  #pragma unroll
  for (int n4 = 0; n4 < 4; n4++)
    #pragma unroll
    for (int r = 0; r < 4; r++)
      So[(size_t)(16*w + 4*fq + r) * 64 + 16*n4 + fr] = f2b(lacc[n4][r]);

  // ---- O_intra = S V ----
  bf16x8 sa[2], vb[4][2];
  #pragma unroll
  for (int kh = 0; kh < 2; kh++)
    sa[kh] = *reinterpret_cast<const bf16x8*>(&Ss[w][fr][kh*32 + fq*8]);
  #pragma unroll
  for (int n4 = 0; n4 < 4; n4++)
    #pragma unroll
    for (int kh = 0; kh < 2; kh++)
      vb[n4][kh] = *reinterpret_cast<const bf16x8*>(Vtb + (size_t)(16*n4 + fr) * LL + kh*32 + fq*8);
  f32x4 oacc[4] = {};
  #pragma unroll
  for (int n4 = 0; n4 < 4; n4++) {
    oacc[n4] = __builtin_amdgcn_mfma_f32_16x16x32_bf16(sa[0], vb[n4][0], oacc[n4], 0, 0, 0);
    oacc[n4] = __builtin_amdgcn_mfma_f32_16x16x32_bf16(sa[1], vb[n4][1], oacc[n4], 0, 0, 0);
  }
  u16* Ob = Oa + (tok0 + 16*w) * DD + h * HD;
  #pragma unroll
  for (int n4 = 0; n4 < 4; n4++)
    #pragma unroll
    for (int r = 0; r < 4; r++)
      Ob[(size_t)(4*fq + r) * DD + 16*n4 + fr] = f2b(oacc[n4][r]);
}

// ---------------- attention phase 2: exclusive fp32 scan ----------------
__global__ __launch_bounds__(256) void attn_phase2(const u16* __restrict__ Slt,
                                                   u16* __restrict__ Wc) {
  const int rg = blockIdx.x, h = blockIdx.y, b = blockIdx.z;
  const size_t base = ((size_t)((b * HH + h) * 16)) * 4096 + rg * 512 + threadIdx.x * 2;
  float r0 = 0.f, r1 = 0.f;
  for (int tl = 0; tl < 16; tl++) {
    const size_t p = base + (size_t)tl * 4096;
    const unsigned d = *reinterpret_cast<const unsigned*>(Slt + p);
    *reinterpret_cast<unsigned*>(Wc + p) = (unsigned)f2b(r0) | ((unsigned)f2b(r1) << 16);
    r0 += b2f((u16)(d & 0xffff));
    r1 += b2f((u16)(d >> 16));
  }
}

// ---------------- attention phase 3: O += Q @ W_prev ----------------
__global__ __launch_bounds__(256) void attn_phase3(const u16* __restrict__ QKV,
                                                   const u16* __restrict__ Wc,
                                                   u16* __restrict__ Oa) {
  const int tile = blockIdx.x, h = blockIdx.y, b = blockIdx.z;
  const int t = threadIdx.x, lane = t & 63, w = t >> 6;
  const int fr = lane & 15, fq = lane >> 4;
  const size_t tok0 = (size_t)(b * LL + tile * 64);
  const size_t bh = (size_t)(b * HH + h);
  const u16* Qb = QKV + tok0 * QS + h * HD;
  const u16* Wb = Wc + (bh * 16 + tile) * 4096;

  bf16x8 aq[2], wb[4][2];
  #pragma unroll
  for (int kh = 0; kh < 2; kh++)
    aq[kh] = *reinterpret_cast<const bf16x8*>(Qb + (size_t)(16*w + fr) * QS + kh*32 + fq*8);
  #pragma unroll
  for (int n4 = 0; n4 < 4; n4++)
    #pragma unroll
    for (int kh = 0; kh < 2; kh++)
      wb[n4][kh] = *reinterpret_cast<const bf16x8*>(Wb + (size_t)(16*n4 + fr) * 64 + kh*32 + fq*8);
  f32x4 oacc[4] = {};
  #pragma unroll
  for (int n4 = 0; n4 < 4; n4++) {
    oacc[n4] = __builtin_amdgcn_mfma_f32_16x16x32_bf16(aq[0], wb[n4][0], oacc[n4], 0, 0, 0);
    oacc[n4] = __builtin_amdgcn_mfma_f32_16x16x32_bf16(aq[1], wb[n4][1], oacc[n4], 0, 0, 0);
  }
  u16* Ob = Oa + (tok0 + 16*w) * DD + h * HD;
  #pragma unroll
  for (int n4 = 0; n4 < 4; n4++)
    #pragma unroll
    for (int r = 0; r < 4; r++) {
      const size_t idx = (size_t)(4*fq + r) * DD + 16*n4 + fr;
      Ob[idx] = f2b(b2f(Ob[idx]) + oacc[n4][r]);
    }
}

// ---------------- host ----------------
// ws map (32 MB): slt 0..4 | wcum 4..8 | h/a/m 8..12 | qkv 12..24 | f 12..28 (qkv/Vt dead)
// | Vt 24..28 | Kt 28..32.  fp32 residual stream lives in d_out.
extern "C" void kernel_launch(void* const* d_in, const int* in_sizes, int n_in,
                              void* d_out, int out_size, void* d_ws, size_t ws_size,
                              hipStream_t stream) {
  const float* x_in = (const float*)d_in[0];
  const float* qw   = (const float*)d_in[1];
  const float* kw   = (const float*)d_in[2];
  const float* vw   = (const float*)d_in[3];
  const float* ow   = (const float*)d_in[4];
  const float* pn   = (const float*)d_in[5];
  const float* ln   = (const float*)d_in[6];
  const float* fcw  = (const float*)d_in[7];
  const float* fc2w = (const float*)d_in[8];
  const float* fc2b = (const float*)d_in[9];

  char* ws = (char*)d_ws;
  u16* slt  = (u16*)ws;
  u16* wcum = (u16*)(ws + (size_t)(4 << 20));
  u16* h    = (u16*)(ws + (size_t)(8 << 20));
  u16* qkv  = (u16*)(ws + (size_t)(12 << 20));
  u16* f    = (u16*)(ws + (size_t)(12 << 20));
  u16* vt   = (u16*)(ws + (size_t)(24 << 20));
  u16* kt   = (u16*)(ws + (size_t)(28 << 20));
  float* xf = (float*)d_out;

  const int gInit = MM * DD / 4 / 256;   // 2048

  for (int i = 0; i < 2; i++) {
    const float* qwi  = qw   + (size_t)i * DD * DD;
    const float* kwi  = kw   + (size_t)i * DD * DD;
    const float* vwi  = vw   + (size_t)i * DD * DD;
    const float* owi  = ow   + (size_t)i * DD * DD;
    const float* fcwi = fcw  + (size_t)i * DFFN * DD;
    const float* f2wi = fc2w + (size_t)i * DD * DFFN;
    const float* src  = (i == 0) ? x_in : xf;

    rmsnorm_kernel<<<MM, 256, 0, stream>>>(src, pn + i * DD, h);
    // fused QKV projection (weights cast in-GEMM)
    mfma_gemm<128, 128, 0, 1><<<dim3(QS / 128, MM / 128), 256, 0, stream>>>(
        h, qwi, kwi, vwi, qkv, QS, DD);
    // chunked linear attention (a = h region)
    kv_trans<<<dim3(16, 32, BB), 256, 0, stream>>>(qkv, kt, vt);
    attn_phase1<<<dim3(16, HH, BB), 256, 0, stream>>>(qkv, kt, vt, h, slt);
    attn_phase2<<<dim3(8, HH, BB), 256, 0, stream>>>(slt, wcum);
    attn_phase3<<<dim3(16, HH, BB), 256, 0, stream>>>(qkv, wcum, h);
    // O-proj: xf = src + a @ ow^T   (split-K 4, atomic accumulate)
    init_out_kernel<<<gInit, 256, 0, stream>>>(xf, src, nullptr);
    mfma_gemm_sk<4><<<dim3(DD / 128, MM / 128, 4), 256, 0, stream>>>(h, owi, xf, DD, DD);
    // MLP
    rmsnorm_kernel<<<MM, 256, 0, stream>>>(xf, ln + i * DD, h);
    mfma_gemm<128, 128, 1, 0><<<dim3(DFFN / 128, MM / 128), 256, 0, stream>>>(
        h, fcwi, fcwi, fcwi, f, DFFN, DD);
    float* co = (i == 1) ? (float*)d_out : xf;
    init_out_kernel<<<gInit, 256, 0, stream>>>(co, xf, fc2b + i * DD);
    mfma_gemm_sk<4><<<dim3(DD / 128, MM / 128, 4), 256, 0, stream>>>(f, f2wi, co, DD, DFFN);
  }
}

// Round 7
// 580.804 us; speedup vs baseline: 1.1748x; 1.1748x over previous
//
#include <hip/hip_runtime.h>

// Problem dims (fixed)
#define BB 2
#define LL 1024
#define DD 1024
#define HH 16
#define HD 64
#define DFFN 4096
#define MM (BB*LL)   // 2048 rows
#define QS 3072      // fused QKV row stride

using u16 = unsigned short;
typedef __bf16 bf16x8 __attribute__((ext_vector_type(8)));
typedef float f32x4 __attribute__((ext_vector_type(4)));

__device__ __forceinline__ float b2f(u16 u) {
  union { unsigned int i; float f; } v; v.i = ((unsigned int)u) << 16; return v.f;
}
__device__ __forceinline__ u16 f2b(float f) {
  union { float f; unsigned int i; } v; v.f = f;
  unsigned int x = v.i;
  return (u16)((x + 0x7fffu + ((x >> 16) & 1u)) >> 16);  // RNE, finite values
}
__device__ __forceinline__ float gelu_exact(float x) {
  return 0.5f * x * (1.0f + erff(x * 0.70710678118654752f));
}
__device__ __forceinline__ void gl2lds16(const void* g, void* l) {
  __builtin_amdgcn_global_load_lds((const __attribute__((address_space(1))) void*)g,
                                   (__attribute__((address_space(3))) void*)l, 16, 0, 0);
}

// ---------------- weight casts fp32 -> bf16 ----------------
__global__ __launch_bounds__(256) void castw_kernel(const float* __restrict__ in,
                                                    u16* __restrict__ out, int n8) {
  int i = blockIdx.x * 256 + threadIdx.x;
  if (i >= n8) return;
  const float4 a = reinterpret_cast<const float4*>(in)[2 * i];
  const float4 b = reinterpret_cast<const float4*>(in)[2 * i + 1];
  uint4 o;
  o.x = (unsigned)f2b(a.x) | ((unsigned)f2b(a.y) << 16);
  o.y = (unsigned)f2b(a.z) | ((unsigned)f2b(a.w) << 16);
  o.z = (unsigned)f2b(b.x) | ((unsigned)f2b(b.y) << 16);
  o.w = (unsigned)f2b(b.z) | ((unsigned)f2b(b.w) << 16);
  reinterpret_cast<uint4*>(out)[i] = o;
}
__global__ __launch_bounds__(256) void castw3_kernel(const float* __restrict__ s0,
                                                     const float* __restrict__ s1,
                                                     const float* __restrict__ s2,
                                                     u16* __restrict__ out, int n8) {
  int i = blockIdx.x * 256 + threadIdx.x;
  if (i >= n8) return;
  const float* in = (blockIdx.y == 0) ? s0 : (blockIdx.y == 1) ? s1 : s2;
  u16* dst = out + (size_t)blockIdx.y * n8 * 8;
  const float4 a = reinterpret_cast<const float4*>(in)[2 * i];
  const float4 b = reinterpret_cast<const float4*>(in)[2 * i + 1];
  uint4 o;
  o.x = (unsigned)f2b(a.x) | ((unsigned)f2b(a.y) << 16);
  o.y = (unsigned)f2b(a.z) | ((unsigned)f2b(a.w) << 16);
  o.z = (unsigned)f2b(b.x) | ((unsigned)f2b(b.y) << 16);
  o.w = (unsigned)f2b(b.z) | ((unsigned)f2b(b.w) << 16);
  reinterpret_cast<uint4*>(dst)[i] = o;
}

// ---------------- out = resid (+ bias), fp32 ----------------
__global__ __launch_bounds__(256) void init_out_kernel(float* __restrict__ out,
                                                       const float* __restrict__ resid,
                                                       const float* __restrict__ bias) {
  const int i = blockIdx.x * 256 + threadIdx.x;   // float4 index
  float4 v = reinterpret_cast<const float4*>(resid)[i];
  if (bias != nullptr) {
    const float4 bv = *reinterpret_cast<const float4*>(bias + ((i * 4) & (DD - 1)));
    v.x += bv.x; v.y += bv.y; v.z += bv.z; v.w += bv.w;
  }
  reinterpret_cast<float4*>(out)[i] = v;
}

// ---------------- rmsnorm (fp32 in, fp32 weight, bf16 out) ----------------
__global__ __launch_bounds__(256) void rmsnorm_kernel(const float* __restrict__ x,
                                                      const float* __restrict__ w,
                                                      u16* __restrict__ out) {
  const int row = blockIdx.x, t = threadIdx.x;
  const float4 v = reinterpret_cast<const float4*>(x + (size_t)row * DD)[t];
  float ss = v.x*v.x + v.y*v.y + v.z*v.z + v.w*v.w;
  #pragma unroll
  for (int o = 32; o > 0; o >>= 1) ss += __shfl_down(ss, o);
  __shared__ float red[4];
  if ((t & 63) == 0) red[t >> 6] = ss;
  __syncthreads();
  const float inv = rsqrtf((red[0] + red[1] + red[2] + red[3]) * (1.0f / DD) + 1e-5f);
  const float4 wv = reinterpret_cast<const float4*>(w)[t];
  ushort4 o;
  o.x = f2b(v.x * inv * wv.x);
  o.y = f2b(v.y * inv * wv.y);
  o.z = f2b(v.z * inv * wv.z);
  o.w = f2b(v.w * inv * wv.w);
  reinterpret_cast<ushort4*>(out + (size_t)row * DD)[t] = o;
}

// ---- BK=64 staging: tile [ROWS][64] bf16, lane-linear (ROWS*8 16B-chunks) ----
template<int ROWS, int NT>
__device__ __forceinline__ void dma64(const u16* __restrict__ g, int r0, int K, int kt,
                                      int t, u16* lds) {
  #pragma unroll
  for (int i = 0; i < ROWS * 8 / NT; i++) {
    const int c = i * NT + t;
    gl2lds16(g + (size_t)(r0 + (c >> 3)) * K + kt + (c & 7) * 8, &lds[c * 8]);
  }
}
// 32 MFMAs per wave over the 64-wide K tile, two kh-halves to bound live VGPRs
__device__ __forceinline__ void mfma_tile64(const u16* Asb, const u16* Bsb,
                                            int wm, int wn, int fr, int fq, f32x4 acc[4][4]) {
  #pragma unroll
  for (int kh = 0; kh < 2; kh++) {
    bf16x8 af[4], bfv[4];
    #pragma unroll
    for (int i = 0; i < 4; i++)
      af[i] = *reinterpret_cast<const bf16x8*>(&Asb[(wm + i * 16 + fr) * 64 + kh * 32 + fq * 8]);
    #pragma unroll
    for (int j = 0; j < 4; j++)
      bfv[j] = *reinterpret_cast<const bf16x8*>(&Bsb[(wn + j * 16 + fr) * 64 + kh * 32 + fq * 8]);
    #pragma unroll
    for (int i = 0; i < 4; i++)
      #pragma unroll
      for (int j = 0; j < 4; j++)
        acc[i][j] = __builtin_amdgcn_mfma_f32_16x16x32_bf16(af[i], bfv[j], acc[i][j], 0, 0, 0);
  }
}

// ---------------- MFMA GEMM: C[M,N](bf16) = A(bf16) @ Wb(bf16,[N,K])^T, BK=64 ----------------
template<int BM, int BN, int ACT>
__global__ __launch_bounds__((BM/64)*(BN/64)*64)
void mfma_gemm(const u16* __restrict__ A, const u16* __restrict__ Wb,
               u16* __restrict__ Cb, int N, int K) {
  constexpr int WCOLS = BN / 64;
  constexpr int NW = (BM / 64) * WCOLS;
  constexpr int NT = NW * 64;
  __shared__ u16 As[BM * 64];
  __shared__ u16 Bs[BN * 64];
  const int t = threadIdx.x;
  const int lane = t & 63, w = t >> 6;
  const int wm = (w / WCOLS) * 64, wn = (w % WCOLS) * 64;
  const int m0 = blockIdx.y * BM, n0 = blockIdx.x * BN;
  const int fr = lane & 15, fq = lane >> 4;

  f32x4 acc[4][4] = {};
  for (int kt = 0; kt < K; kt += 64) {
    dma64<BM, NT>(A, m0, K, kt, t, As);
    dma64<BN, NT>(Wb, n0, K, kt, t, Bs);
    __syncthreads();   // vmcnt drained at barrier -> tiles complete
    mfma_tile64(As, Bs, wm, wn, fr, fq, acc);
    __syncthreads();   // reads done before next tile's DMA
  }

  #pragma unroll
  for (int i = 0; i < 4; i++)
    #pragma unroll
    for (int j = 0; j < 4; j++)
      #pragma unroll
      for (int r = 0; r < 4; r++) {
        const int row = m0 + wm + i * 16 + fq * 4 + r;
        const int col = n0 + wn + j * 16 + fr;
        float val = acc[i][j][r];
        if (ACT == 1) val = gelu_exact(val);
        Cb[(size_t)row * N + col] = f2b(val);
      }
}

// ---------------- split-K MFMA GEMM, BK=64: Co(f32) += A @ Wb^T  (Co pre-initialized) ----------------
template<int SPLIT>
__global__ __launch_bounds__(256)
void mfma_gemm_sk(const u16* __restrict__ A, const u16* __restrict__ Wb,
                  float* __restrict__ Co, int N, int K) {
  constexpr int BM = 128, BN = 128, NT = 256;
  __shared__ u16 As[BM * 64];
  __shared__ u16 Bs[BN * 64];
  const int t = threadIdx.x;
  const int lane = t & 63, w = t >> 6;
  const int wm = (w >> 1) * 64, wn = (w & 1) * 64;
  const int m0 = blockIdx.y * BM, n0 = blockIdx.x * BN;
  const int fr = lane & 15, fq = lane >> 4;
  const int Kc = K / SPLIT, k0 = blockIdx.z * Kc, kend = k0 + Kc;

  f32x4 acc[4][4] = {};
  for (int kt = k0; kt < kend; kt += 64) {
    dma64<BM, NT>(A, m0, K, kt, t, As);
    dma64<BN, NT>(Wb, n0, K, kt, t, Bs);
    __syncthreads();
    mfma_tile64(As, Bs, wm, wn, fr, fq, acc);
    __syncthreads();
  }

  #pragma unroll
  for (int i = 0; i < 4; i++)
    #pragma unroll
    for (int j = 0; j < 4; j++)
      #pragma unroll
      for (int r = 0; r < 4; r++) {
        const int row = m0 + wm + i * 16 + fq * 4 + r;
        const int col = n0 + wn + j * 16 + fr;
        unsafeAtomicAdd(&Co[(size_t)row * N + col], acc[i][j][r]);
      }
}

// ---------------- K/V transpose via LDS, coalesced both sides ----------------
__global__ __launch_bounds__(256) void kv_trans(const u16* __restrict__ QKV,
                                                u16* __restrict__ Kt, u16* __restrict__ Vt) {
  __shared__ u16 T[64][72];
  const int tile = blockIdx.x;
  const int h2 = blockIdx.y;             // h = h2&15, which = h2>>4 (0=K, 1=V)
  const int b = blockIdx.z;
  const int h = h2 & 15, which = h2 >> 4;
  const int t = threadIdx.x;
  const int pos = t >> 2, d0 = (t & 3) * 16;
  const u16* src = QKV + ((size_t)(b * LL) + tile * 64 + pos) * QS + 1024 + which * 1024 + h * HD + d0;
  union { uint4 u[2]; u16 s[16]; } pk;
  pk.u[0] = reinterpret_cast<const uint4*>(src)[0];
  pk.u[1] = reinterpret_cast<const uint4*>(src)[1];
  #pragma unroll
  for (int j = 0; j < 16; j++) T[d0 + j][pos] = pk.s[j];
  __syncthreads();
  const int d = t >> 2, p0 = (t & 3) * 16;
  u16* dst = (which ? Vt : Kt) + ((size_t)(b * HH + h) * HD + d) * LL + tile * 64 + p0;
  union { uint4 u[2]; u16 s[16]; } ok;
  #pragma unroll
  for (int j = 0; j < 16; j++) ok.s[j] = T[d][p0 + j];
  reinterpret_cast<uint4*>(dst)[0] = ok.u[0];
  reinterpret_cast<uint4*>(dst)[1] = ok.u[1];
}

// ---------------- attention phase 1 ----------------
__global__ __launch_bounds__(256) void attn_phase1(const u16* __restrict__ QKV,
                                                   const u16* __restrict__ Kt,
                                                   const u16* __restrict__ Vt,
                                                   u16* __restrict__ Oa,
                                                   u16* __restrict__ Slt) {
  __shared__ u16 Ss[4][16][64];
  const int tile = blockIdx.x, h = blockIdx.y, b = blockIdx.z;
  const int t = threadIdx.x, lane = t & 63, w = t >> 6;
  const int fr = lane & 15, fq = lane >> 4;
  const size_t tok0 = (size_t)(b * LL + tile * 64);
  const size_t bh = (size_t)(b * HH + h);
  const u16* Qb  = QKV + tok0 * QS + h * HD;
  const u16* Kb  = Qb + 1024;
  const u16* Ktb = Kt + bh * (HD * LL) + tile * 64;
  const u16* Vtb = Vt + bh * (HD * LL) + tile * 64;

  // ---- S = Q K^T ----
  bf16x8 aq[2], bk[4][2];
  #pragma unroll
  for (int kh = 0; kh < 2; kh++)
    aq[kh] = *reinterpret_cast<const bf16x8*>(Qb + (size_t)(16*w + fr) * QS + kh*32 + fq*8);
  #pragma unroll
  for (int n4 = 0; n4 < 4; n4++)
    #pragma unroll
    for (int kh = 0; kh < 2; kh++)
      bk[n4][kh] = *reinterpret_cast<const bf16x8*>(Kb + (size_t)(16*n4 + fr) * QS + kh*32 + fq*8);
  f32x4 sacc[4] = {};
  #pragma unroll
  for (int n4 = 0; n4 < 4; n4++) {
    sacc[n4] = __builtin_amdgcn_mfma_f32_16x16x32_bf16(aq[0], bk[n4][0], sacc[n4], 0, 0, 0);
    sacc[n4] = __builtin_amdgcn_mfma_f32_16x16x32_bf16(aq[1], bk[n4][1], sacc[n4], 0, 0, 0);
  }
  #pragma unroll
  for (int n4 = 0; n4 < 4; n4++)
    #pragma unroll
    for (int r = 0; r < 4; r++) {
      const bool keep = (16*w + 4*fq + r) >= (16*n4 + fr);
      Ss[w][4*fq + r][16*n4 + fr] = keep ? f2b(sacc[n4][r]) : (u16)0;
    }
  __syncthreads();

  // ---- Slt = V^T K ----
  bf16x8 va[2], kt[4][2];
  #pragma unroll
  for (int kh = 0; kh < 2; kh++)
    va[kh] = *reinterpret_cast<const bf16x8*>(Vtb + (size_t)(16*w + fr) * LL + kh*32 + fq*8);
  #pragma unroll
  for (int n4 = 0; n4 < 4; n4++)
    #pragma unroll
    for (int kh = 0; kh < 2; kh++)
      kt[n4][kh] = *reinterpret_cast<const bf16x8*>(Ktb + (size_t)(16*n4 + fr) * LL + kh*32 + fq*8);
  f32x4 lacc[4] = {};
  #pragma unroll
  for (int n4 = 0; n4 < 4; n4++) {
    lacc[n4] = __builtin_amdgcn_mfma_f32_16x16x32_bf16(va[0], kt[n4][0], lacc[n4], 0, 0, 0);
    lacc[n4] = __builtin_amdgcn_mfma_f32_16x16x32_bf16(va[1], kt[n4][1], lacc[n4], 0, 0, 0);
  }
  u16* So = Slt + (bh * 16 + tile) * 4096;
  #pragma unroll
  for (int n4 = 0; n4 < 4; n4++)
    #pragma unroll
    for (int r = 0; r < 4; r++)
      So[(size_t)(16*w + 4*fq + r) * 64 + 16*n4 + fr] = f2b(lacc[n4][r]);

  // ---- O_intra = S V ----
  bf16x8 sa[2], vb[4][2];
  #pragma unroll
  for (int kh = 0; kh < 2; kh++)
    sa[kh] = *reinterpret_cast<const bf16x8*>(&Ss[w][fr][kh*32 + fq*8]);
  #pragma unroll
  for (int n4 = 0; n4 < 4; n4++)
    #pragma unroll
    for (int kh = 0; kh < 2; kh++)
      vb[n4][kh] = *reinterpret_cast<const bf16x8*>(Vtb + (size_t)(16*n4 + fr) * LL + kh*32 + fq*8);
  f32x4 oacc[4] = {};
  #pragma unroll
  for (int n4 = 0; n4 < 4; n4++) {
    oacc[n4] = __builtin_amdgcn_mfma_f32_16x16x32_bf16(sa[0], vb[n4][0], oacc[n4], 0, 0, 0);
    oacc[n4] = __builtin_amdgcn_mfma_f32_16x16x32_bf16(sa[1], vb[n4][1], oacc[n4], 0, 0, 0);
  }
  u16* Ob = Oa + (tok0 + 16*w) * DD + h * HD;
  #pragma unroll
  for (int n4 = 0; n4 < 4; n4++)
    #pragma unroll
    for (int r = 0; r < 4; r++)
      Ob[(size_t)(4*fq + r) * DD + 16*n4 + fr] = f2b(oacc[n4][r]);
}

// ---------------- attention phase 2: exclusive fp32 scan ----------------
__global__ __launch_bounds__(256) void attn_phase2(const u16* __restrict__ Slt,
                                                   u16* __restrict__ Wc) {
  const int rg = blockIdx.x, h = blockIdx.y, b = blockIdx.z;
  const size_t base = ((size_t)((b * HH + h) * 16)) * 4096 + rg * 512 + threadIdx.x * 2;
  float r0 = 0.f, r1 = 0.f;
  for (int tl = 0; tl < 16; tl++) {
    const size_t p = base + (size_t)tl * 4096;
    const unsigned d = *reinterpret_cast<const unsigned*>(Slt + p);
    *reinterpret_cast<unsigned*>(Wc + p) = (unsigned)f2b(r0) | ((unsigned)f2b(r1) << 16);
    r0 += b2f((u16)(d & 0xffff));
    r1 += b2f((u16)(d >> 16));
  }
}

// ---------------- attention phase 3: O += Q @ W_prev ----------------
__global__ __launch_bounds__(256) void attn_phase3(const u16* __restrict__ QKV,
                                                   const u16* __restrict__ Wc,
                                                   u16* __restrict__ Oa) {
  const int tile = blockIdx.x, h = blockIdx.y, b = blockIdx.z;
  const int t = threadIdx.x, lane = t & 63, w = t >> 6;
  const int fr = lane & 15, fq = lane >> 4;
  const size_t tok0 = (size_t)(b * LL + tile * 64);
  const size_t bh = (size_t)(b * HH + h);
  const u16* Qb = QKV + tok0 * QS + h * HD;
  const u16* Wb = Wc + (bh * 16 + tile) * 4096;

  bf16x8 aq[2], wb[4][2];
  #pragma unroll
  for (int kh = 0; kh < 2; kh++)
    aq[kh] = *reinterpret_cast<const bf16x8*>(Qb + (size_t)(16*w + fr) * QS + kh*32 + fq*8);
  #pragma unroll
  for (int n4 = 0; n4 < 4; n4++)
    #pragma unroll
    for (int kh = 0; kh < 2; kh++)
      wb[n4][kh] = *reinterpret_cast<const bf16x8*>(Wb + (size_t)(16*n4 + fr) * 64 + kh*32 + fq*8);
  f32x4 oacc[4] = {};
  #pragma unroll
  for (int n4 = 0; n4 < 4; n4++) {
    oacc[n4] = __builtin_amdgcn_mfma_f32_16x16x32_bf16(aq[0], wb[n4][0], oacc[n4], 0, 0, 0);
    oacc[n4] = __builtin_amdgcn_mfma_f32_16x16x32_bf16(aq[1], wb[n4][1], oacc[n4], 0, 0, 0);
  }
  u16* Ob = Oa + (tok0 + 16*w) * DD + h * HD;
  #pragma unroll
  for (int n4 = 0; n4 < 4; n4++)
    #pragma unroll
    for (int r = 0; r < 4; r++) {
      const size_t idx = (size_t)(4*fq + r) * DD + 16*n4 + fr;
      Ob[idx] = f2b(b2f(Ob[idx]) + oacc[n4][r]);
    }
}

// ---------------- host ----------------
// ws map (32 MB): wbuf 0..8 (time-shared with Slt 0..4 / Wcum 4..8 during attn)
// h/a/m 8..12 | qkv 12..24 | f 12..28 (qkv/Vt dead) | Vt 24..28 | Kt 28..32
// fp32 residual stream lives in d_out.
extern "C" void kernel_launch(void* const* d_in, const int* in_sizes, int n_in,
                              void* d_out, int out_size, void* d_ws, size_t ws_size,
                              hipStream_t stream) {
  const float* x_in = (const float*)d_in[0];
  const float* qw   = (const float*)d_in[1];
  const float* kw   = (const float*)d_in[2];
  const float* vw   = (const float*)d_in[3];
  const float* ow   = (const float*)d_in[4];
  const float* pn   = (const float*)d_in[5];
  const float* ln   = (const float*)d_in[6];
  const float* fcw  = (const float*)d_in[7];
  const float* fc2w = (const float*)d_in[8];
  const float* fc2b = (const float*)d_in[9];

  char* ws = (char*)d_ws;
  u16* wbuf = (u16*)ws;
  u16* slt  = (u16*)ws;
  u16* wcum = (u16*)(ws + (size_t)(4 << 20));
  u16* h    = (u16*)(ws + (size_t)(8 << 20));
  u16* qkv  = (u16*)(ws + (size_t)(12 << 20));
  u16* f    = (u16*)(ws + (size_t)(12 << 20));
  u16* vt   = (u16*)(ws + (size_t)(24 << 20));
  u16* kt   = (u16*)(ws + (size_t)(28 << 20));
  float* xf = (float*)d_out;

  const int n8D = DD * DD / 8;
  const int n8F = DFFN * DD / 8;
  const int gInit = MM * DD / 4 / 256;   // 2048

  for (int i = 0; i < 2; i++) {
    const float* qwi  = qw   + (size_t)i * DD * DD;
    const float* kwi  = kw   + (size_t)i * DD * DD;
    const float* vwi  = vw   + (size_t)i * DD * DD;
    const float* owi  = ow   + (size_t)i * DD * DD;
    const float* fcwi = fcw  + (size_t)i * DFFN * DD;
    const float* f2wi = fc2w + (size_t)i * DD * DFFN;
    const float* src  = (i == 0) ? x_in : xf;

    rmsnorm_kernel<<<MM, 256, 0, stream>>>(src, pn + i * DD, h);
    // fused QKV projection: 64x128 tiles -> 768 blocks (3/CU uniform)
    castw3_kernel<<<dim3(n8D / 256, 3), 256, 0, stream>>>(qwi, kwi, vwi, wbuf, n8D);
    mfma_gemm<64, 128, 0><<<dim3(QS / 128, MM / 64), 128, 0, stream>>>(
        h, wbuf, qkv, QS, DD);
    // chunked linear attention (a = h region)
    kv_trans<<<dim3(16, 32, BB), 256, 0, stream>>>(qkv, kt, vt);
    attn_phase1<<<dim3(16, HH, BB), 256, 0, stream>>>(qkv, kt, vt, h, slt);
    attn_phase2<<<dim3(8, HH, BB), 256, 0, stream>>>(slt, wcum);
    attn_phase3<<<dim3(16, HH, BB), 256, 0, stream>>>(qkv, wcum, h);
    // O-proj: xf = src + a @ ow^T  (split-K 4)
    castw_kernel<<<n8D / 256, 256, 0, stream>>>(owi, wbuf, n8D);
    init_out_kernel<<<gInit, 256, 0, stream>>>(xf, src, nullptr);
    mfma_gemm_sk<4><<<dim3(DD / 128, MM / 128, 4), 256, 0, stream>>>(h, wbuf, xf, DD, DD);
    // MLP
    rmsnorm_kernel<<<MM, 256, 0, stream>>>(xf, ln + i * DD, h);
    castw_kernel<<<n8F / 256, 256, 0, stream>>>(fcwi, wbuf, n8F);
    // FC1: 64x128 tiles -> 1024 blocks (4/CU)
    mfma_gemm<64, 128, 1><<<dim3(DFFN / 128, MM / 64), 128, 0, stream>>>(
        h, wbuf, f, DFFN, DD);
    castw_kernel<<<n8F / 256, 256, 0, stream>>>(f2wi, wbuf, n8F);
    float* co = (i == 1) ? (float*)d_out : xf;
    init_out_kernel<<<gInit, 256, 0, stream>>>(co, xf, fc2b + i * DD);
    // FC2: split-K 8 -> 1024 blocks
    mfma_gemm_sk<8><<<dim3(DD / 128, MM / 128, 8), 256, 0, stream>>>(f, wbuf, co, DD, DFFN);
  }
}

// Round 8
// 538.616 us; speedup vs baseline: 1.2668x; 1.0783x over previous
//
#include <hip/hip_runtime.h>

// Problem dims (fixed)
#define BB 2
#define LL 1024
#define DD 1024
#define HH 16
#define HD 64
#define DFFN 4096
#define MM (BB*LL)   // 2048 rows
#define QS 3072      // fused QKV row stride

using u16 = unsigned short;
typedef __bf16 bf16x8 __attribute__((ext_vector_type(8)));
typedef float f32x4 __attribute__((ext_vector_type(4)));

__device__ __forceinline__ float b2f(u16 u) {
  union { unsigned int i; float f; } v; v.i = ((unsigned int)u) << 16; return v.f;
}
__device__ __forceinline__ u16 f2b(float f) {
  union { float f; unsigned int i; } v; v.f = f;
  unsigned int x = v.i;
  return (u16)((x + 0x7fffu + ((x >> 16) & 1u)) >> 16);  // RNE, finite values
}
__device__ __forceinline__ float gelu_exact(float x) {
  return 0.5f * x * (1.0f + erff(x * 0.70710678118654752f));
}
__device__ __forceinline__ void gl2lds16(const void* g, void* l) {
  __builtin_amdgcn_global_load_lds((const __attribute__((address_space(1))) void*)g,
                                   (__attribute__((address_space(3))) void*)l, 16, 0, 0);
}

// ---------------- weight casts fp32 -> bf16 ----------------
__global__ __launch_bounds__(256) void castw_kernel(const float* __restrict__ in,
                                                    u16* __restrict__ out, int n8) {
  int i = blockIdx.x * 256 + threadIdx.x;
  if (i >= n8) return;
  const float4 a = reinterpret_cast<const float4*>(in)[2 * i];
  const float4 b = reinterpret_cast<const float4*>(in)[2 * i + 1];
  uint4 o;
  o.x = (unsigned)f2b(a.x) | ((unsigned)f2b(a.y) << 16);
  o.y = (unsigned)f2b(a.z) | ((unsigned)f2b(a.w) << 16);
  o.z = (unsigned)f2b(b.x) | ((unsigned)f2b(b.y) << 16);
  o.w = (unsigned)f2b(b.z) | ((unsigned)f2b(b.w) << 16);
  reinterpret_cast<uint4*>(out)[i] = o;
}
__global__ __launch_bounds__(256) void castw3_kernel(const float* __restrict__ s0,
                                                     const float* __restrict__ s1,
                                                     const float* __restrict__ s2,
                                                     u16* __restrict__ out, int n8) {
  int i = blockIdx.x * 256 + threadIdx.x;
  if (i >= n8) return;
  const float* in = (blockIdx.y == 0) ? s0 : (blockIdx.y == 1) ? s1 : s2;
  u16* dst = out + (size_t)blockIdx.y * n8 * 8;
  const float4 a = reinterpret_cast<const float4*>(in)[2 * i];
  const float4 b = reinterpret_cast<const float4*>(in)[2 * i + 1];
  uint4 o;
  o.x = (unsigned)f2b(a.x) | ((unsigned)f2b(a.y) << 16);
  o.y = (unsigned)f2b(a.z) | ((unsigned)f2b(a.w) << 16);
  o.z = (unsigned)f2b(b.x) | ((unsigned)f2b(b.y) << 16);
  o.w = (unsigned)f2b(b.z) | ((unsigned)f2b(b.w) << 16);
  reinterpret_cast<uint4*>(dst)[i] = o;
}

// ---------------- out = resid (+ bias), fp32 ----------------
__global__ __launch_bounds__(256) void init_out_kernel(float* __restrict__ out,
                                                       const float* __restrict__ resid,
                                                       const float* __restrict__ bias) {
  const int i = blockIdx.x * 256 + threadIdx.x;   // float4 index
  float4 v = reinterpret_cast<const float4*>(resid)[i];
  if (bias != nullptr) {
    const float4 bv = *reinterpret_cast<const float4*>(bias + ((i * 4) & (DD - 1)));
    v.x += bv.x; v.y += bv.y; v.z += bv.z; v.w += bv.w;
  }
  reinterpret_cast<float4*>(out)[i] = v;
}

// ---------------- rmsnorm (fp32 in, fp32 weight, bf16 out) ----------------
__global__ __launch_bounds__(256) void rmsnorm_kernel(const float* __restrict__ x,
                                                      const float* __restrict__ w,
                                                      u16* __restrict__ out) {
  const int row = blockIdx.x, t = threadIdx.x;
  const float4 v = reinterpret_cast<const float4*>(x + (size_t)row * DD)[t];
  float ss = v.x*v.x + v.y*v.y + v.z*v.z + v.w*v.w;
  #pragma unroll
  for (int o = 32; o > 0; o >>= 1) ss += __shfl_down(ss, o);
  __shared__ float red[4];
  if ((t & 63) == 0) red[t >> 6] = ss;
  __syncthreads();
  const float inv = rsqrtf((red[0] + red[1] + red[2] + red[3]) * (1.0f / DD) + 1e-5f);
  const float4 wv = reinterpret_cast<const float4*>(w)[t];
  ushort4 o;
  o.x = f2b(v.x * inv * wv.x);
  o.y = f2b(v.y * inv * wv.y);
  o.z = f2b(v.z * inv * wv.z);
  o.w = f2b(v.w * inv * wv.w);
  reinterpret_cast<ushort4*>(out + (size_t)row * DD)[t] = o;
}

// ---- BK=32 staging: tile [ROWS][32] bf16, lane-linear (ROWS*4 16B-chunks) ----
template<int ROWS, int NT>
__device__ __forceinline__ void dma32(const u16* __restrict__ g, int r0, int K, int kt,
                                      int t, u16* lds) {
  #pragma unroll
  for (int i = 0; i < ROWS * 4 / NT; i++) {
    const int c = i * NT + t;
    gl2lds16(g + (size_t)(r0 + (c >> 2)) * K + kt + (c & 3) * 8, &lds[c * 8]);
  }
}
__device__ __forceinline__ void mfma_tile32(const u16* Asb, const u16* Bsb,
                                            int wm, int wn, int fr, int fq, f32x4 acc[4][4]) {
  bf16x8 af[4], bfv[4];
  #pragma unroll
  for (int i = 0; i < 4; i++)
    af[i] = *reinterpret_cast<const bf16x8*>(&Asb[(wm + i * 16 + fr) * 32 + fq * 8]);
  #pragma unroll
  for (int j = 0; j < 4; j++)
    bfv[j] = *reinterpret_cast<const bf16x8*>(&Bsb[(wn + j * 16 + fr) * 32 + fq * 8]);
  #pragma unroll
  for (int i = 0; i < 4; i++)
    #pragma unroll
    for (int j = 0; j < 4; j++)
      acc[i][j] = __builtin_amdgcn_mfma_f32_16x16x32_bf16(af[i], bfv[j], acc[i][j], 0, 0, 0);
}

// ---------------- MFMA GEMM: C[M,N](bf16) = A(bf16) @ Wb(bf16,[N,K])^T ----------------
// 128x64 tile, 128 threads (2 waves, 64x64 each) -> 2x block count vs 128x128.
template<int BM, int BN, int ACT>
__global__ __launch_bounds__((BM/64)*(BN/64)*64)
void mfma_gemm(const u16* __restrict__ A, const u16* __restrict__ Wb,
               u16* __restrict__ Cb, int N, int K) {
  constexpr int WCOLS = BN / 64;
  constexpr int NW = (BM / 64) * WCOLS;
  constexpr int NT = NW * 64;
  __shared__ u16 As[BM * 32];
  __shared__ u16 Bs[BN * 32];
  const int t = threadIdx.x;
  const int lane = t & 63, w = t >> 6;
  const int wm = (w / WCOLS) * 64, wn = (w % WCOLS) * 64;
  const int m0 = blockIdx.y * BM, n0 = blockIdx.x * BN;
  const int fr = lane & 15, fq = lane >> 4;

  f32x4 acc[4][4] = {};
  for (int kt = 0; kt < K; kt += 32) {
    dma32<BM, NT>(A, m0, K, kt, t, As);
    dma32<BN, NT>(Wb, n0, K, kt, t, Bs);
    __syncthreads();   // vmcnt drained at barrier -> tiles complete
    mfma_tile32(As, Bs, wm, wn, fr, fq, acc);
    __syncthreads();   // reads done before next tile's DMA
  }

  #pragma unroll
  for (int i = 0; i < 4; i++)
    #pragma unroll
    for (int j = 0; j < 4; j++)
      #pragma unroll
      for (int r = 0; r < 4; r++) {
        const int row = m0 + wm + i * 16 + fq * 4 + r;
        const int col = n0 + wn + j * 16 + fr;
        float val = acc[i][j][r];
        if (ACT == 1) val = gelu_exact(val);
        Cb[(size_t)row * N + col] = f2b(val);
      }
}

// ---------------- split-K MFMA GEMM: Co(f32) += A @ Wb^T  (Co pre-initialized) ----------------
// 128x64 tile, 128 threads.
template<int SPLIT>
__global__ __launch_bounds__(128)
void mfma_gemm_sk(const u16* __restrict__ A, const u16* __restrict__ Wb,
                  float* __restrict__ Co, int N, int K) {
  constexpr int BM = 128, BN = 64, NT = 128;
  __shared__ u16 As[BM * 32];
  __shared__ u16 Bs[BN * 32];
  const int t = threadIdx.x;
  const int lane = t & 63, w = t >> 6;
  const int wm = w * 64, wn = 0;
  const int m0 = blockIdx.y * BM, n0 = blockIdx.x * BN;
  const int fr = lane & 15, fq = lane >> 4;
  const int Kc = K / SPLIT, k0 = blockIdx.z * Kc, kend = k0 + Kc;

  f32x4 acc[4][4] = {};
  for (int kt = k0; kt < kend; kt += 32) {
    dma32<BM, NT>(A, m0, K, kt, t, As);
    dma32<BN, NT>(Wb, n0, K, kt, t, Bs);
    __syncthreads();
    mfma_tile32(As, Bs, wm, wn, fr, fq, acc);
    __syncthreads();
  }

  #pragma unroll
  for (int i = 0; i < 4; i++)
    #pragma unroll
    for (int j = 0; j < 4; j++)
      #pragma unroll
      for (int r = 0; r < 4; r++) {
        const int row = m0 + wm + i * 16 + fq * 4 + r;
        const int col = n0 + wn + j * 16 + fr;
        unsafeAtomicAdd(&Co[(size_t)row * N + col], acc[i][j][r]);
      }
}

// ---------------- K/V transpose via LDS, coalesced both sides ----------------
__global__ __launch_bounds__(256) void kv_trans(const u16* __restrict__ QKV,
                                                u16* __restrict__ Kt, u16* __restrict__ Vt) {
  __shared__ u16 T[64][72];
  const int tile = blockIdx.x;
  const int h2 = blockIdx.y;             // h = h2&15, which = h2>>4 (0=K, 1=V)
  const int b = blockIdx.z;
  const int h = h2 & 15, which = h2 >> 4;
  const int t = threadIdx.x;
  const int pos = t >> 2, d0 = (t & 3) * 16;
  const u16* src = QKV + ((size_t)(b * LL) + tile * 64 + pos) * QS + 1024 + which * 1024 + h * HD + d0;
  union { uint4 u[2]; u16 s[16]; } pk;
  pk.u[0] = reinterpret_cast<const uint4*>(src)[0];
  pk.u[1] = reinterpret_cast<const uint4*>(src)[1];
  #pragma unroll
  for (int j = 0; j < 16; j++) T[d0 + j][pos] = pk.s[j];
  __syncthreads();
  const int d = t >> 2, p0 = (t & 3) * 16;
  u16* dst = (which ? Vt : Kt) + ((size_t)(b * HH + h) * HD + d) * LL + tile * 64 + p0;
  union { uint4 u[2]; u16 s[16]; } ok;
  #pragma unroll
  for (int j = 0; j < 16; j++) ok.s[j] = T[d][p0 + j];
  reinterpret_cast<uint4*>(dst)[0] = ok.u[0];
  reinterpret_cast<uint4*>(dst)[1] = ok.u[1];
}

// ---------------- attention phase 1 ----------------
__global__ __launch_bounds__(256) void attn_phase1(const u16* __restrict__ QKV,
                                                   const u16* __restrict__ Kt,
                                                   const u16* __restrict__ Vt,
                                                   u16* __restrict__ Oa,
                                                   u16* __restrict__ Slt) {
  __shared__ u16 Ss[4][16][64];
  const int tile = blockIdx.x, h = blockIdx.y, b = blockIdx.z;
  const int t = threadIdx.x, lane = t & 63, w = t >> 6;
  const int fr = lane & 15, fq = lane >> 4;
  const size_t tok0 = (size_t)(b * LL + tile * 64);
  const size_t bh = (size_t)(b * HH + h);
  const u16* Qb  = QKV + tok0 * QS + h * HD;
  const u16* Kb  = Qb + 1024;
  const u16* Ktb = Kt + bh * (HD * LL) + tile * 64;
  const u16* Vtb = Vt + bh * (HD * LL) + tile * 64;

  // ---- S = Q K^T ----
  bf16x8 aq[2], bk[4][2];
  #pragma unroll
  for (int kh = 0; kh < 2; kh++)
    aq[kh] = *reinterpret_cast<const bf16x8*>(Qb + (size_t)(16*w + fr) * QS + kh*32 + fq*8);
  #pragma unroll
  for (int n4 = 0; n4 < 4; n4++)
    #pragma unroll
    for (int kh = 0; kh < 2; kh++)
      bk[n4][kh] = *reinterpret_cast<const bf16x8*>(Kb + (size_t)(16*n4 + fr) * QS + kh*32 + fq*8);
  f32x4 sacc[4] = {};
  #pragma unroll
  for (int n4 = 0; n4 < 4; n4++) {
    sacc[n4] = __builtin_amdgcn_mfma_f32_16x16x32_bf16(aq[0], bk[n4][0], sacc[n4], 0, 0, 0);
    sacc[n4] = __builtin_amdgcn_mfma_f32_16x16x32_bf16(aq[1], bk[n4][1], sacc[n4], 0, 0, 0);
  }
  #pragma unroll
  for (int n4 = 0; n4 < 4; n4++)
    #pragma unroll
    for (int r = 0; r < 4; r++) {
      const bool keep = (16*w + 4*fq + r) >= (16*n4 + fr);
      Ss[w][4*fq + r][16*n4 + fr] = keep ? f2b(sacc[n4][r]) : (u16)0;
    }
  __syncthreads();

  // ---- Slt = V^T K ----
  bf16x8 va[2], kt[4][2];
  #pragma unroll
  for (int kh = 0; kh < 2; kh++)
    va[kh] = *reinterpret_cast<const bf16x8*>(Vtb + (size_t)(16*w + fr) * LL + kh*32 + fq*8);
  #pragma unroll
  for (int n4 = 0; n4 < 4; n4++)
    #pragma unroll
    for (int kh = 0; kh < 2; kh++)
      kt[n4][kh] = *reinterpret_cast<const bf16x8*>(Ktb + (size_t)(16*n4 + fr) * LL + kh*32 + fq*8);
  f32x4 lacc[4] = {};
  #pragma unroll
  for (int n4 = 0; n4 < 4; n4++) {
    lacc[n4] = __builtin_amdgcn_mfma_f32_16x16x32_bf16(va[0], kt[n4][0], lacc[n4], 0, 0, 0);
    lacc[n4] = __builtin_amdgcn_mfma_f32_16x16x32_bf16(va[1], kt[n4][1], lacc[n4], 0, 0, 0);
  }
  u16* So = Slt + (bh * 16 + tile) * 4096;
  #pragma unroll
  for (int n4 = 0; n4 < 4; n4++)
    #pragma unroll
    for (int r = 0; r < 4; r++)
      So[(size_t)(16*w + 4*fq + r) * 64 + 16*n4 + fr] = f2b(lacc[n4][r]);

  // ---- O_intra = S V ----
  bf16x8 sa[2], vb[4][2];
  #pragma unroll
  for (int kh = 0; kh < 2; kh++)
    sa[kh] = *reinterpret_cast<const bf16x8*>(&Ss[w][fr][kh*32 + fq*8]);
  #pragma unroll
  for (int n4 = 0; n4 < 4; n4++)
    #pragma unroll
    for (int kh = 0; kh < 2; kh++)
      vb[n4][kh] = *reinterpret_cast<const bf16x8*>(Vtb + (size_t)(16*n4 + fr) * LL + kh*32 + fq*8);
  f32x4 oacc[4] = {};
  #pragma unroll
  for (int n4 = 0; n4 < 4; n4++) {
    oacc[n4] = __builtin_amdgcn_mfma_f32_16x16x32_bf16(sa[0], vb[n4][0], oacc[n4], 0, 0, 0);
    oacc[n4] = __builtin_amdgcn_mfma_f32_16x16x32_bf16(sa[1], vb[n4][1], oacc[n4], 0, 0, 0);
  }
  u16* Ob = Oa + (tok0 + 16*w) * DD + h * HD;
  #pragma unroll
  for (int n4 = 0; n4 < 4; n4++)
    #pragma unroll
    for (int r = 0; r < 4; r++)
      Ob[(size_t)(4*fq + r) * DD + 16*n4 + fr] = f2b(oacc[n4][r]);
}

// ---------------- attention phase 2: exclusive fp32 scan ----------------
__global__ __launch_bounds__(256) void attn_phase2(const u16* __restrict__ Slt,
                                                   u16* __restrict__ Wc) {
  const int rg = blockIdx.x, h = blockIdx.y, b = blockIdx.z;
  const size_t base = ((size_t)((b * HH + h) * 16)) * 4096 + rg * 512 + threadIdx.x * 2;
  float r0 = 0.f, r1 = 0.f;
  for (int tl = 0; tl < 16; tl++) {
    const size_t p = base + (size_t)tl * 4096;
    const unsigned d = *reinterpret_cast<const unsigned*>(Slt + p);
    *reinterpret_cast<unsigned*>(Wc + p) = (unsigned)f2b(r0) | ((unsigned)f2b(r1) << 16);
    r0 += b2f((u16)(d & 0xffff));
    r1 += b2f((u16)(d >> 16));
  }
}

// ---------------- attention phase 3: O += Q @ W_prev ----------------
__global__ __launch_bounds__(256) void attn_phase3(const u16* __restrict__ QKV,
                                                   const u16* __restrict__ Wc,
                                                   u16* __restrict__ Oa) {
  const int tile = blockIdx.x, h = blockIdx.y, b = blockIdx.z;
  const int t = threadIdx.x, lane = t & 63, w = t >> 6;
  const int fr = lane & 15, fq = lane >> 4;
  const size_t tok0 = (size_t)(b * LL + tile * 64);
  const size_t bh = (size_t)(b * HH + h);
  const u16* Qb = QKV + tok0 * QS + h * HD;
  const u16* Wb = Wc + (bh * 16 + tile) * 4096;

  bf16x8 aq[2], wb[4][2];
  #pragma unroll
  for (int kh = 0; kh < 2; kh++)
    aq[kh] = *reinterpret_cast<const bf16x8*>(Qb + (size_t)(16*w + fr) * QS + kh*32 + fq*8);
  #pragma unroll
  for (int n4 = 0; n4 < 4; n4++)
    #pragma unroll
    for (int kh = 0; kh < 2; kh++)
      wb[n4][kh] = *reinterpret_cast<const bf16x8*>(Wb + (size_t)(16*n4 + fr) * 64 + kh*32 + fq*8);
  f32x4 oacc[4] = {};
  #pragma unroll
  for (int n4 = 0; n4 < 4; n4++) {
    oacc[n4] = __builtin_amdgcn_mfma_f32_16x16x32_bf16(aq[0], wb[n4][0], oacc[n4], 0, 0, 0);
    oacc[n4] = __builtin_amdgcn_mfma_f32_16x16x32_bf16(aq[1], wb[n4][1], oacc[n4], 0, 0, 0);
  }
  u16* Ob = Oa + (tok0 + 16*w) * DD + h * HD;
  #pragma unroll
  for (int n4 = 0; n4 < 4; n4++)
    #pragma unroll
    for (int r = 0; r < 4; r++) {
      const size_t idx = (size_t)(4*fq + r) * DD + 16*n4 + fr;
      Ob[idx] = f2b(b2f(Ob[idx]) + oacc[n4][r]);
    }
}

// ---------------- host ----------------
// ws map (32 MB): wbuf 0..8 (time-shared with Slt 0..4 / Wcum 4..8 during attn)
// h/a/m 8..12 | qkv 12..24 | f 12..28 (qkv/Vt dead) | Vt 24..28 | Kt 28..32
// fp32 residual stream lives in d_out.
extern "C" void kernel_launch(void* const* d_in, const int* in_sizes, int n_in,
                              void* d_out, int out_size, void* d_ws, size_t ws_size,
                              hipStream_t stream) {
  const float* x_in = (const float*)d_in[0];
  const float* qw   = (const float*)d_in[1];
  const float* kw   = (const float*)d_in[2];
  const float* vw   = (const float*)d_in[3];
  const float* ow   = (const float*)d_in[4];
  const float* pn   = (const float*)d_in[5];
  const float* ln   = (const float*)d_in[6];
  const float* fcw  = (const float*)d_in[7];
  const float* fc2w = (const float*)d_in[8];
  const float* fc2b = (const float*)d_in[9];

  char* ws = (char*)d_ws;
  u16* wbuf = (u16*)ws;
  u16* slt  = (u16*)ws;
  u16* wcum = (u16*)(ws + (size_t)(4 << 20));
  u16* h    = (u16*)(ws + (size_t)(8 << 20));
  u16* qkv  = (u16*)(ws + (size_t)(12 << 20));
  u16* f    = (u16*)(ws + (size_t)(12 << 20));
  u16* vt   = (u16*)(ws + (size_t)(24 << 20));
  u16* kt   = (u16*)(ws + (size_t)(28 << 20));
  float* xf = (float*)d_out;

  const int n8D = DD * DD / 8;
  const int n8F = DFFN * DD / 8;
  const int gInit = MM * DD / 4 / 256;   // 2048

  for (int i = 0; i < 2; i++) {
    const float* qwi  = qw   + (size_t)i * DD * DD;
    const float* kwi  = kw   + (size_t)i * DD * DD;
    const float* vwi  = vw   + (size_t)i * DD * DD;
    const float* owi  = ow   + (size_t)i * DD * DD;
    const float* fcwi = fcw  + (size_t)i * DFFN * DD;
    const float* f2wi = fc2w + (size_t)i * DD * DFFN;
    const float* src  = (i == 0) ? x_in : xf;

    rmsnorm_kernel<<<MM, 256, 0, stream>>>(src, pn + i * DD, h);
    // fused QKV projection: 128x64 tiles -> 768 blocks (3/CU)
    castw3_kernel<<<dim3(n8D / 256, 3), 256, 0, stream>>>(qwi, kwi, vwi, wbuf, n8D);
    mfma_gemm<128, 64, 0><<<dim3(QS / 64, MM / 128), 128, 0, stream>>>(
        h, wbuf, qkv, QS, DD);
    // chunked linear attention (a = h region)
    kv_trans<<<dim3(16, 32, BB), 256, 0, stream>>>(qkv, kt, vt);
    attn_phase1<<<dim3(16, HH, BB), 256, 0, stream>>>(qkv, kt, vt, h, slt);
    attn_phase2<<<dim3(8, HH, BB), 256, 0, stream>>>(slt, wcum);
    attn_phase3<<<dim3(16, HH, BB), 256, 0, stream>>>(qkv, wcum, h);
    // O-proj: xf = src + a @ ow^T  (split-K 2 -> 512 blocks)
    castw_kernel<<<n8D / 256, 256, 0, stream>>>(owi, wbuf, n8D);
    init_out_kernel<<<gInit, 256, 0, stream>>>(xf, src, nullptr);
    mfma_gemm_sk<2><<<dim3(DD / 64, MM / 128, 2), 128, 0, stream>>>(h, wbuf, xf, DD, DD);
    // MLP
    rmsnorm_kernel<<<MM, 256, 0, stream>>>(xf, ln + i * DD, h);
    castw_kernel<<<n8F / 256, 256, 0, stream>>>(fcwi, wbuf, n8F);
    // FC1: 128x64 tiles -> 1024 blocks (4/CU)
    mfma_gemm<128, 64, 1><<<dim3(DFFN / 64, MM / 128), 128, 0, stream>>>(
        h, wbuf, f, DFFN, DD);
    castw_kernel<<<n8F / 256, 256, 0, stream>>>(f2wi, wbuf, n8F);
    float* co = (i == 1) ? (float*)d_out : xf;
    init_out_kernel<<<gInit, 256, 0, stream>>>(co, xf, fc2b + i * DD);
    // FC2: split-K 4 -> 1024 blocks (4/CU)
    mfma_gemm_sk<4><<<dim3(DD / 64, MM / 128, 4), 128, 0, stream>>>(f, wbuf, co, DD, DFFN);
  }
}